// Round 14
// baseline (352.224 us; speedup 1.0000x reference)
//
#include <hip/hip_runtime.h>
#include <hip/hip_bf16.h>

// ---------------------------------------------------------------------------
// Swin WindowAttention fused kernel, v14 = v13 + QK depth-2 + deferred norm.
//   - QK merged swapped pass now has the FULL depth-2 pipeline (wnxt AND
//     xnxt): v13 dropped the LDS prefetch when merging -> ~130cyc ds_read
//     exposure per iter. Restored (v10-proven pattern).
//   - Softmax normalization deferred through PV (linearity): pB holds
//     unnormalized e=exp(s-m)<=1; rs[qt] scales oT after PV (per-lane q-row
//     mapping matches PV output col=c). 64 v_mul off the critical path.
//   - Rest = v13: swapped QK (zero transposes), xs2 double-buffer
//     (2 barriers), V/proj depth-2 pipelines, V(0) prefetch under softmax
//     tail, proj B(0) prefetch before barrier, sb/sm split tables, K=16 PV,
//     setprio, launch_bounds(512,2). VGPR cap=256/arg2; waves/SIMD
//     quantized {8,4,2} at VGPR {<=64,<=128,<=256} -> 4/SIMD is our ceiling.
// ---------------------------------------------------------------------------

#define NTOK 49
static constexpr float SCALE_Q = 0.17677669529663687f; // 32^-0.5

using bf16   = __bf16;
using bf16x4 = __attribute__((ext_vector_type(4))) __bf16;
using bf16x8 = __attribute__((ext_vector_type(8))) __bf16;
using short4v = __attribute__((ext_vector_type(4))) short;
using f32x4  = __attribute__((ext_vector_type(4))) float;

#define WT_QKV_OFF 0
#define WT_PROJ_OFF (768 * 256 * 2)
#define SB_OFF (WT_PROJ_OFF + 256 * 256 * 2)
#define SM_OFF (SB_OFF + 8 * 4096 * 4)
#define WS_NEEDED (SM_OFF + (size_t)64 * 4096 * 4)

// ---- 16x16x16 bf16 MFMA wrapper (builtin-name portability) ----
static __device__ __forceinline__ f32x4 mfma16(bf16x4 a, bf16x4 b, f32x4 c) {
#if __has_builtin(__builtin_amdgcn_mfma_f32_16x16x16_bf16)
    return __builtin_amdgcn_mfma_f32_16x16x16_bf16(a, b, c, 0, 0, 0);
#elif __has_builtin(__builtin_amdgcn_mfma_f32_16x16x16bf16_1k)
    return __builtin_amdgcn_mfma_f32_16x16x16bf16_1k(
        __builtin_bit_cast(short4v, a), __builtin_bit_cast(short4v, b), c, 0, 0, 0);
#elif __has_builtin(__builtin_amdgcn_mfma_f32_16x16x16_bf16_1k)
    return __builtin_amdgcn_mfma_f32_16x16x16_bf16_1k(
        __builtin_bit_cast(short4v, a), __builtin_bit_cast(short4v, b), c, 0, 0, 0);
#else
    asm volatile("v_mfma_f32_16x16x16_bf16 %0, %1, %2, %0\n\t"
                 "s_nop 7\n\ts_nop 7\n\ts_nop 1"
                 : "+v"(c) : "v"(a), "v"(b));
    return c;
#endif
}

static __device__ __forceinline__ bf16x8 ldsA(const char* base, int row, int koff) {
    return *(const bf16x8*)(base + row * 512 + (koff ^ ((row & 7) << 4)));
}
static __device__ __forceinline__ bf16x8 ldB(const bf16* wt, int ncol, int k2, int hf, int g) {
    return *(const bf16x8*)(wt + ncol * 256 + k2 * 64 + hf * 32 + g * 8);
}

// ---- precompute kernels ----
__global__ void prep_wqkv(const float* __restrict__ qkv_w, bf16* __restrict__ wt) {
    int idx = blockIdx.x * 256 + threadIdx.x;            // 768*256
    if (idx >= 768 * 256) return;
    int n = idx >> 8, k = idx & 255;
    float v = qkv_w[k * 768 + n];
    if (n < 256) v *= SCALE_Q;                           // fold q-scale
    wt[idx] = (bf16)v;                                   // wt[n][k]
}
__global__ void prep_wproj(const float* __restrict__ proj_w, bf16* __restrict__ wt) {
    int idx = blockIdx.x * 256 + threadIdx.x;            // 256*256
    if (idx >= 256 * 256) return;
    int n = idx >> 8, k = idx & 255;
    wt[idx] = (bf16)proj_w[k * 256 + n];                 // wt[n][k]
}
// sb[h][qp][lane][r]: rel-bias part for q=16qt+(lane&15), key=16kt+4*(lane>>4)+r
// (qp = kt*4+qt). -1e30 for key>=49 (pad); 0 for q>=49 (dead rows).
__global__ void prep_sb(const float* __restrict__ bias_table, const int* __restrict__ rel_index,
                        float* __restrict__ sb) {
    int idx = blockIdx.x * 256 + threadIdx.x;            // 8*4096
    if (idx >= 8 * 4096) return;
    int r    = idx & 3;
    int lane = (idx >> 2) & 63;
    int qp   = (idx >> 8) & 15;
    int h    = idx >> 12;
    int kt = qp >> 2, qt = qp & 3;
    int i = qt * 16 + (lane & 15);
    int j = kt * 16 + (lane >> 4) * 4 + r;
    float v;
    if (j >= NTOK)      v = -1e30f;
    else if (i >= NTOK) v = 0.0f;
    else v = bias_table[rel_index[i * 49 + j] * 8 + h];
    sb[idx] = v;
}
// sm[w][qp][lane][r]: window-mask part (0 on padded rows/cols).
__global__ void prep_sm(const float* __restrict__ mask, float* __restrict__ sm) {
    int idx = blockIdx.x * 256 + threadIdx.x;            // 64*4096
    if (idx >= 64 * 4096) return;
    int r    = idx & 3;
    int lane = (idx >> 2) & 63;
    int qp   = (idx >> 8) & 15;
    int w    = idx >> 12;
    int kt = qp >> 2, qt = qp & 3;
    int i = qt * 16 + (lane & 15);
    int j = kt * 16 + (lane >> 4) * 4 + r;
    sm[idx] = (i < NTOK && j < NTOK) ? mask[(w * 49 + i) * 49 + j] : 0.0f;
}

__global__ __launch_bounds__(512, 2) void fused_attn(
    const float* __restrict__ x,
    const float* __restrict__ qkv_b,
    const float* __restrict__ proj_b,
    const bf16* __restrict__ wt_qkv,
    const bf16* __restrict__ wt_proj,
    const float* __restrict__ sb,
    const float* __restrict__ sm,
    float* __restrict__ out)
{
    __shared__ char smem[65536];
    char* xs  = smem;            // x tile (bf16, swizzled)
    char* xs2 = smem + 32768;    // attn-out tile (bf16, swizzled)
    const int b    = blockIdx.x;
    const int tid  = threadIdx.x;
    const int lane = tid & 63;
    const int h    = tid >> 6;       // wave id == head
    const int c    = lane & 15;
    const int g    = lane >> 4;

    // chan-tile base for merged QK swapped pass: mt 0,1 = Q; mt 2,3 = K
    auto cbase = [&](int mt) {
        return (mt < 2 ? h * 32 + mt * 16 : 256 + h * 32 + (mt - 2) * 16) + c;
    };

    // ---- issue QK weight preload (kk=0) BEFORE stage barrier (no xs dep) --
    bf16x8 wcur[4], wnxt[4];
    #pragma unroll
    for (int mt = 0; mt < 4; ++mt)
        wcur[mt] = *(const bf16x8*)(wt_qkv + cbase(mt) * 256 + g * 8);

    // ---- stage x -> xs: 8 reg-loads batched, then cvt+write ----
    {
        const float* xb = x + (size_t)b * (NTOK * 256);
        float4 xr[8];
        #pragma unroll
        for (int it = 0; it < 8; ++it) {
            int idx = it * 512 + tid;          // 64 rows x 64 float4-chunks
            int row = idx >> 6, c4 = idx & 63;
            xr[it] = make_float4(0.f, 0.f, 0.f, 0.f);
            if (row < NTOK) xr[it] = ((const float4*)xb)[row * 64 + c4];
        }
        #pragma unroll
        for (int it = 0; it < 8; ++it) {
            int idx = it * 512 + tid;
            int row = idx >> 6, c4 = idx & 63;
            bf16x4 o;
            o[0] = (bf16)xr[it].x; o[1] = (bf16)xr[it].y;
            o[2] = (bf16)xr[it].z; o[3] = (bf16)xr[it].w;
            *(bf16x4*)(xs + row * 512 + ((c4 * 8) ^ ((row & 7) << 4))) = o;
        }
    }
    __syncthreads();

    bf16x4 qf[4][2];   // [qt(token)][ct(chan)] B-frag for scores
    bf16x4 kf[4][2];   // [kt(token)][ct(chan)] A-frag for scores
    bf16x4 pB[4][4];   // [qt][kt]  UNNORMALIZED e == PV B-frag (parks thru V)
    float  rsv[4];     // [qt] 1/sum, applied to oT after PV
    bf16x4 vf[2][4];   // [dt][kt]  A-frag for PV

    // ---- merged QK pass (SWAPPED, depth-2 on BOTH streams): BK=32 ----
    //   C'[chan=4g+r (+16*mt)][token=c (+16*nt)] == scores frag layout.
    {
        f32x4 acc[4][4];   // [mt][nt]
        #pragma unroll
        for (int mt = 0; mt < 4; ++mt)
            #pragma unroll
            for (int nt = 0; nt < 4; ++nt)
                acc[mt][nt] = (f32x4){0.f, 0.f, 0.f, 0.f};

        bf16x8 xcur[4], xnxt[4];
        #pragma unroll
        for (int nt = 0; nt < 4; ++nt)
            xcur[nt] = ldsA(xs, nt * 16 + c, g * 16);

        #pragma unroll
        for (int kk = 0; kk < 8; ++kk) {
            if (kk < 7) {
                #pragma unroll
                for (int mt = 0; mt < 4; ++mt)
                    wnxt[mt] = *(const bf16x8*)(wt_qkv + cbase(mt) * 256 + (kk + 1) * 32 + g * 8);
                #pragma unroll
                for (int nt = 0; nt < 4; ++nt)
                    xnxt[nt] = ldsA(xs, nt * 16 + c, (kk + 1) * 64 + g * 16);
            }
            #pragma unroll
            for (int mt = 0; mt < 4; ++mt)
                #pragma unroll
                for (int nt = 0; nt < 4; ++nt)
                    acc[mt][nt] = __builtin_amdgcn_mfma_f32_16x16x32_bf16(wcur[mt], xcur[nt], acc[mt][nt], 0, 0, 0);
            if (kk < 7) {
                #pragma unroll
                for (int mt = 0; mt < 4; ++mt) wcur[mt] = wnxt[mt];
                #pragma unroll
                for (int nt = 0; nt < 4; ++nt) xcur[nt] = xnxt[nt];
            }
        }
        // epilogue: +bias (per-chan, one float4 per tile); NO transpose.
        #pragma unroll
        for (int mt = 0; mt < 2; ++mt) {
            f32x4 bq = *(const f32x4*)(qkv_b + h * 32 + mt * 16 + 4 * g);
            #pragma unroll
            for (int nt = 0; nt < 4; ++nt)
                #pragma unroll
                for (int r = 0; r < 4; ++r)
                    qf[nt][mt][r] = (bf16)(acc[mt][nt][r] + bq[r] * SCALE_Q);
        }
        #pragma unroll
        for (int mt = 0; mt < 2; ++mt) {
            f32x4 bk = *(const f32x4*)(qkv_b + 256 + h * 32 + mt * 16 + 4 * g);
            #pragma unroll
            for (int nt = 0; nt < 4; ++nt)
                #pragma unroll
                for (int r = 0; r < 4; ++r)
                    kf[nt][mt][r] = (bf16)(acc[mt + 2][nt][r] + bk[r]);
        }
    }

    const int colV = 512 + h * 32 + c;

    // pipeline registers for V / proj passes
    bf16x8 bcur[2][2], bnxt[2][2];        // [ni][hf]
    bf16x8 acur[2][4], anxt[2][4];        // [hf][mi]

    // ---- scores + softmax (per qt; last qt prefetches V(0)) ----
    {
        const float* sbh = sb + (size_t)h * 4096;
        const float* smw = sm + (size_t)(b & 63) * 4096;
        #pragma unroll
        for (int qt = 0; qt < 4; ++qt) {
            f32x4 sbv[4], smv[4];
            #pragma unroll
            for (int kt = 0; kt < 4; ++kt)
                sbv[kt] = *(const f32x4*)(sbh + (kt * 4 + qt) * 256 + lane * 4);
            #pragma unroll
            for (int kt = 0; kt < 4; ++kt)
                smv[kt] = *(const f32x4*)(smw + (kt * 4 + qt) * 256 + lane * 4);

            f32x4 sT[4];
            __builtin_amdgcn_s_setprio(1);
            #pragma unroll
            for (int kt = 0; kt < 4; ++kt) {
                sT[kt] = (f32x4){0.f, 0.f, 0.f, 0.f};
                sT[kt] = mfma16(kf[kt][0], qf[qt][0], sT[kt]);
                sT[kt] = mfma16(kf[kt][1], qf[qt][1], sT[kt]);
            }
            __builtin_amdgcn_s_setprio(0);
            if (qt == 3) {   // prefetch V's k2=0 under the softmax tail
                #pragma unroll
                for (int ni = 0; ni < 2; ++ni)
                    #pragma unroll
                    for (int hf = 0; hf < 2; ++hf)
                        bcur[ni][hf] = ldB(wt_qkv, colV + ni * 16, 0, hf, g);
                #pragma unroll
                for (int hf = 0; hf < 2; ++hf)
                    #pragma unroll
                    for (int mi = 0; mi < 4; ++mi)
                        acur[hf][mi] = ldsA(xs, mi * 16 + c, hf * 64 + g * 16);
            }
            #pragma unroll
            for (int kt = 0; kt < 4; ++kt)
                #pragma unroll
                for (int r = 0; r < 4; ++r)
                    sT[kt][r] += sbv[kt][r] + smv[kt][r];
            // tree max over the 16 in-lane values, then cross-lane
            f32x4 mx4;
            #pragma unroll
            for (int r = 0; r < 4; ++r)
                mx4[r] = fmaxf(fmaxf(sT[0][r], sT[1][r]), fmaxf(sT[2][r], sT[3][r]));
            float m = fmaxf(fmaxf(mx4[0], mx4[1]), fmaxf(mx4[2], mx4[3]));
            m = fmaxf(m, __shfl_xor(m, 16));
            m = fmaxf(m, __shfl_xor(m, 32));
            f32x4 sm4 = (f32x4){0.f, 0.f, 0.f, 0.f};
            #pragma unroll
            for (int kt = 0; kt < 4; ++kt)
                #pragma unroll
                for (int r = 0; r < 4; ++r) {
                    float e = __expf(sT[kt][r] - m);
                    sT[kt][r] = e;
                    sm4[r] += e;
                }
            float sum = (sm4[0] + sm4[1]) + (sm4[2] + sm4[3]);
            sum += __shfl_xor(sum, 16);
            sum += __shfl_xor(sum, 32);
            rsv[qt] = 1.f / sum;
            // store UNNORMALIZED e (<=1, bf16-safe); norm folded into oT
            #pragma unroll
            for (int kt = 0; kt < 4; ++kt)
                #pragma unroll
                for (int r = 0; r < 4; ++r) pB[qt][kt][r] = (bf16)sT[kt][r];
        }
    }

    // ---- pass V (normal orientation; pipelined; bcur/acur hold V(0)) ----
    {
        f32x4 acc[2][4];
        #pragma unroll
        for (int dt = 0; dt < 2; ++dt)
            #pragma unroll
            for (int mi = 0; mi < 4; ++mi)
                acc[dt][mi] = (f32x4){0.f, 0.f, 0.f, 0.f};
        #pragma unroll
        for (int k2 = 0; k2 < 4; ++k2) {
            if (k2 < 3) {
                #pragma unroll
                for (int dt = 0; dt < 2; ++dt)
                    #pragma unroll
                    for (int hf = 0; hf < 2; ++hf)
                        bnxt[dt][hf] = ldB(wt_qkv, colV + dt * 16, k2 + 1, hf, g);
                #pragma unroll
                for (int hf = 0; hf < 2; ++hf)
                    #pragma unroll
                    for (int mi = 0; mi < 4; ++mi)
                        anxt[hf][mi] = ldsA(xs, mi * 16 + c, (k2 + 1) * 128 + hf * 64 + g * 16);
            }
            #pragma unroll
            for (int hf = 0; hf < 2; ++hf)
                #pragma unroll
                for (int dt = 0; dt < 2; ++dt)
                    #pragma unroll
                    for (int mi = 0; mi < 4; ++mi)
                        acc[dt][mi] = __builtin_amdgcn_mfma_f32_16x16x32_bf16(acur[hf][mi], bcur[dt][hf], acc[dt][mi], 0, 0, 0);
            if (k2 < 3) {
                #pragma unroll
                for (int dt = 0; dt < 2; ++dt)
                    #pragma unroll
                    for (int hf = 0; hf < 2; ++hf)
                        bcur[dt][hf] = bnxt[dt][hf];
                #pragma unroll
                for (int hf = 0; hf < 2; ++hf)
                    #pragma unroll
                    for (int mi = 0; mi < 4; ++mi)
                        acur[hf][mi] = anxt[hf][mi];
            }
        }
        #pragma unroll
        for (int dt = 0; dt < 2; ++dt) {
            float vb = qkv_b[512 + h * 32 + dt * 16 + c];
            #pragma unroll
            for (int kt = 0; kt < 4; ++kt)
                #pragma unroll
                for (int r = 0; r < 4; ++r) vf[dt][kt][r] = (bf16)(acc[dt][kt][r] + vb);
        }
    }

    // ---- PV: write straight to xs2; fold 1/sum here ----
    __builtin_amdgcn_s_setprio(1);
    #pragma unroll
    for (int qt = 0; qt < 4; ++qt) {
        int row = qt * 16 + c;
        #pragma unroll
        for (int dt = 0; dt < 2; ++dt) {
            f32x4 oT = (f32x4){0.f, 0.f, 0.f, 0.f};
            #pragma unroll
            for (int kt = 0; kt < 4; ++kt)
                oT = mfma16(vf[dt][kt], pB[qt][kt], oT);
            int cbyte = h * 64 + dt * 32 + g * 8;
            bf16x4 o;
            #pragma unroll
            for (int r = 0; r < 4; ++r) o[r] = (bf16)(oT[r] * rsv[qt]);
            *(bf16x4*)(xs2 + row * 512 + (cbyte ^ ((row & 7) << 4))) = o;
        }
    }
    __builtin_amdgcn_s_setprio(0);

    // prefetch proj's B(0) before the barrier (global load, no LDS dep)
    #pragma unroll
    for (int ni = 0; ni < 2; ++ni)
        #pragma unroll
        for (int hf = 0; hf < 2; ++hf)
            bcur[ni][hf] = ldB(wt_proj, h * 32 + ni * 16 + c, 0, hf, g);

    __syncthreads();   // single barrier: all PV writes to xs2 visible

    // ---- proj (pipelined; bcur holds proj(0); A from xs2) ----
    {
        f32x4 po[2][4];
        #pragma unroll
        for (int ni = 0; ni < 2; ++ni)
            #pragma unroll
            for (int mi = 0; mi < 4; ++mi)
                po[ni][mi] = (f32x4){0.f, 0.f, 0.f, 0.f};

        #pragma unroll
        for (int hf = 0; hf < 2; ++hf)
            #pragma unroll
            for (int mi = 0; mi < 4; ++mi)
                acur[hf][mi] = ldsA(xs2, mi * 16 + c, hf * 64 + g * 16);

        #pragma unroll
        for (int k2 = 0; k2 < 4; ++k2) {
            if (k2 < 3) {
                #pragma unroll
                for (int ni = 0; ni < 2; ++ni)
                    #pragma unroll
                    for (int hf = 0; hf < 2; ++hf)
                        bnxt[ni][hf] = ldB(wt_proj, h * 32 + ni * 16 + c, k2 + 1, hf, g);
                #pragma unroll
                for (int hf = 0; hf < 2; ++hf)
                    #pragma unroll
                    for (int mi = 0; mi < 4; ++mi)
                        anxt[hf][mi] = ldsA(xs2, mi * 16 + c, (k2 + 1) * 128 + hf * 64 + g * 16);
            }
            #pragma unroll
            for (int hf = 0; hf < 2; ++hf)
                #pragma unroll
                for (int ni = 0; ni < 2; ++ni)
                    #pragma unroll
                    for (int mi = 0; mi < 4; ++mi)
                        po[ni][mi] = __builtin_amdgcn_mfma_f32_16x16x32_bf16(acur[hf][mi], bcur[ni][hf], po[ni][mi], 0, 0, 0);
            if (k2 < 3) {
                #pragma unroll
                for (int ni = 0; ni < 2; ++ni)
                    #pragma unroll
                    for (int hf = 0; hf < 2; ++hf)
                        bcur[ni][hf] = bnxt[ni][hf];
                #pragma unroll
                for (int hf = 0; hf < 2; ++hf)
                    #pragma unroll
                    for (int mi = 0; mi < 4; ++mi)
                        acur[hf][mi] = anxt[hf][mi];
            }
        }
        float* outb = out + (size_t)b * (NTOK * 256);
        #pragma unroll
        for (int ni = 0; ni < 2; ++ni) {
            int col = h * 32 + ni * 16 + c;
            float pb = proj_b[col];
            #pragma unroll
            for (int mi = 0; mi < 4; ++mi) {
                #pragma unroll
                for (int r = 0; r < 4; ++r) {
                    int row = mi * 16 + g * 4 + r;
                    if (row < NTOK) outb[row * 256 + col] = po[ni][mi][r] + pb;
                }
            }
        }
    }
}

extern "C" void kernel_launch(void* const* d_in, const int* in_sizes, int n_in,
                              void* d_out, int out_size, void* d_ws, size_t ws_size,
                              hipStream_t stream) {
    const float* x          = (const float*)d_in[0];
    const float* mask       = (const float*)d_in[1];
    const float* qkv_w      = (const float*)d_in[2];
    const float* qkv_b      = (const float*)d_in[3];
    const float* proj_w     = (const float*)d_in[4];
    const float* proj_b     = (const float*)d_in[5];
    const float* bias_table = (const float*)d_in[6];
    const int*   rel_index  = (const int*)d_in[7];
    float* out = (float*)d_out;

    if (ws_size < WS_NEEDED) return;  // needs ~1.7 MB scratch

    char* ws = (char*)d_ws;
    bf16*  wt_qkv  = (bf16*)(ws + WT_QKV_OFF);
    bf16*  wt_proj = (bf16*)(ws + WT_PROJ_OFF);
    float* sbp     = (float*)(ws + SB_OFF);
    float* smp     = (float*)(ws + SM_OFF);

    prep_wqkv <<<768, 256, 0, stream>>>(qkv_w, wt_qkv);
    prep_wproj<<<256, 256, 0, stream>>>(proj_w, wt_proj);
    prep_sb   <<<128, 256, 0, stream>>>(bias_table, rel_index, sbp);
    prep_sm   <<<1024, 256, 0, stream>>>(mask, smp);

    fused_attn<<<4096, 512, 0, stream>>>(x, qkv_b, proj_b, wt_qkv, wt_proj, sbp, smp, out);
}

// Round 15
// 343.928 us; speedup vs baseline: 1.0241x; 1.0241x over previous
//
#include <hip/hip_runtime.h>
#include <hip/hip_bf16.h>

// ---------------------------------------------------------------------------
// Swin WindowAttention fused kernel, v15 = v14 with RE-ROLLED K-loops.
//   - Hypothesis: fully-unrolled body (~40KB) exceeds 32KB L1I; every wave
//     streams it once -> I-fetch stalls explain the "all pipes <25%, wave
//     runnable ~6%" profile. Rolling QK(x8)/V(x4)/proj(x4) K-iterations into
//     real loops (trip N-1 + tail, depth-2 pipeline preserved, all register
//     arrays statically indexed per rule #20) cuts code ~3-4x to fit L1I.
//   - scores/PV qt-loops stay unrolled (they index pB[qt]; rolling would
//     send pB to scratch).
//   - Everything else = v14: swapped QK (no transposes), deferred softmax
//     norm, xs2 double-buffer (2 barriers), V(0) prefetch under softmax
//     tail, proj B(0) prefetch before barrier, sb/sm split tables, K=16 PV,
//     setprio, launch_bounds(512,2).
// ---------------------------------------------------------------------------

#define NTOK 49
static constexpr float SCALE_Q = 0.17677669529663687f; // 32^-0.5

using bf16   = __bf16;
using bf16x4 = __attribute__((ext_vector_type(4))) __bf16;
using bf16x8 = __attribute__((ext_vector_type(8))) __bf16;
using short4v = __attribute__((ext_vector_type(4))) short;
using f32x4  = __attribute__((ext_vector_type(4))) float;

#define WT_QKV_OFF 0
#define WT_PROJ_OFF (768 * 256 * 2)
#define SB_OFF (WT_PROJ_OFF + 256 * 256 * 2)
#define SM_OFF (SB_OFF + 8 * 4096 * 4)
#define WS_NEEDED (SM_OFF + (size_t)64 * 4096 * 4)

// ---- 16x16x16 bf16 MFMA wrapper (builtin-name portability) ----
static __device__ __forceinline__ f32x4 mfma16(bf16x4 a, bf16x4 b, f32x4 c) {
#if __has_builtin(__builtin_amdgcn_mfma_f32_16x16x16_bf16)
    return __builtin_amdgcn_mfma_f32_16x16x16_bf16(a, b, c, 0, 0, 0);
#elif __has_builtin(__builtin_amdgcn_mfma_f32_16x16x16bf16_1k)
    return __builtin_amdgcn_mfma_f32_16x16x16bf16_1k(
        __builtin_bit_cast(short4v, a), __builtin_bit_cast(short4v, b), c, 0, 0, 0);
#elif __has_builtin(__builtin_amdgcn_mfma_f32_16x16x16_bf16_1k)
    return __builtin_amdgcn_mfma_f32_16x16x16_bf16_1k(
        __builtin_bit_cast(short4v, a), __builtin_bit_cast(short4v, b), c, 0, 0, 0);
#else
    asm volatile("v_mfma_f32_16x16x16_bf16 %0, %1, %2, %0\n\t"
                 "s_nop 7\n\ts_nop 7\n\ts_nop 1"
                 : "+v"(c) : "v"(a), "v"(b));
    return c;
#endif
}

static __device__ __forceinline__ bf16x8 ldsA(const char* base, int row, int koff) {
    return *(const bf16x8*)(base + row * 512 + (koff ^ ((row & 7) << 4)));
}
static __device__ __forceinline__ bf16x8 ldB(const bf16* wt, int ncol, int k2, int hf, int g) {
    return *(const bf16x8*)(wt + ncol * 256 + k2 * 64 + hf * 32 + g * 8);
}

// ---- precompute kernels ----
__global__ void prep_wqkv(const float* __restrict__ qkv_w, bf16* __restrict__ wt) {
    int idx = blockIdx.x * 256 + threadIdx.x;            // 768*256
    if (idx >= 768 * 256) return;
    int n = idx >> 8, k = idx & 255;
    float v = qkv_w[k * 768 + n];
    if (n < 256) v *= SCALE_Q;                           // fold q-scale
    wt[idx] = (bf16)v;                                   // wt[n][k]
}
__global__ void prep_wproj(const float* __restrict__ proj_w, bf16* __restrict__ wt) {
    int idx = blockIdx.x * 256 + threadIdx.x;            // 256*256
    if (idx >= 256 * 256) return;
    int n = idx >> 8, k = idx & 255;
    wt[idx] = (bf16)proj_w[k * 256 + n];                 // wt[n][k]
}
// sb[h][qp][lane][r]: rel-bias part for q=16qt+(lane&15), key=16kt+4*(lane>>4)+r
// (qp = kt*4+qt). -1e30 for key>=49 (pad); 0 for q>=49 (dead rows).
__global__ void prep_sb(const float* __restrict__ bias_table, const int* __restrict__ rel_index,
                        float* __restrict__ sb) {
    int idx = blockIdx.x * 256 + threadIdx.x;            // 8*4096
    if (idx >= 8 * 4096) return;
    int r    = idx & 3;
    int lane = (idx >> 2) & 63;
    int qp   = (idx >> 8) & 15;
    int h    = idx >> 12;
    int kt = qp >> 2, qt = qp & 3;
    int i = qt * 16 + (lane & 15);
    int j = kt * 16 + (lane >> 4) * 4 + r;
    float v;
    if (j >= NTOK)      v = -1e30f;
    else if (i >= NTOK) v = 0.0f;
    else v = bias_table[rel_index[i * 49 + j] * 8 + h];
    sb[idx] = v;
}
// sm[w][qp][lane][r]: window-mask part (0 on padded rows/cols).
__global__ void prep_sm(const float* __restrict__ mask, float* __restrict__ sm) {
    int idx = blockIdx.x * 256 + threadIdx.x;            // 64*4096
    if (idx >= 64 * 4096) return;
    int r    = idx & 3;
    int lane = (idx >> 2) & 63;
    int qp   = (idx >> 8) & 15;
    int w    = idx >> 12;
    int kt = qp >> 2, qt = qp & 3;
    int i = qt * 16 + (lane & 15);
    int j = kt * 16 + (lane >> 4) * 4 + r;
    sm[idx] = (i < NTOK && j < NTOK) ? mask[(w * 49 + i) * 49 + j] : 0.0f;
}

__global__ __launch_bounds__(512, 2) void fused_attn(
    const float* __restrict__ x,
    const float* __restrict__ qkv_b,
    const float* __restrict__ proj_b,
    const bf16* __restrict__ wt_qkv,
    const bf16* __restrict__ wt_proj,
    const float* __restrict__ sb,
    const float* __restrict__ sm,
    float* __restrict__ out)
{
    __shared__ char smem[65536];
    char* xs  = smem;            // x tile (bf16, swizzled)
    char* xs2 = smem + 32768;    // attn-out tile (bf16, swizzled)
    const int b    = blockIdx.x;
    const int tid  = threadIdx.x;
    const int lane = tid & 63;
    const int h    = tid >> 6;       // wave id == head
    const int c    = lane & 15;
    const int g    = lane >> 4;

    // chan-tile base for merged QK swapped pass: mt 0,1 = Q; mt 2,3 = K
    auto cbase = [&](int mt) {
        return (mt < 2 ? h * 32 + mt * 16 : 256 + h * 32 + (mt - 2) * 16) + c;
    };

    // ---- issue QK weight preload (kk=0) BEFORE stage barrier (no xs dep) --
    bf16x8 wcur[4], wnxt[4];
    #pragma unroll
    for (int mt = 0; mt < 4; ++mt)
        wcur[mt] = *(const bf16x8*)(wt_qkv + cbase(mt) * 256 + g * 8);

    // ---- stage x -> xs: 8 reg-loads batched, then cvt+write ----
    {
        const float* xb = x + (size_t)b * (NTOK * 256);
        float4 xr[8];
        #pragma unroll
        for (int it = 0; it < 8; ++it) {
            int idx = it * 512 + tid;          // 64 rows x 64 float4-chunks
            int row = idx >> 6, c4 = idx & 63;
            xr[it] = make_float4(0.f, 0.f, 0.f, 0.f);
            if (row < NTOK) xr[it] = ((const float4*)xb)[row * 64 + c4];
        }
        #pragma unroll
        for (int it = 0; it < 8; ++it) {
            int idx = it * 512 + tid;
            int row = idx >> 6, c4 = idx & 63;
            bf16x4 o;
            o[0] = (bf16)xr[it].x; o[1] = (bf16)xr[it].y;
            o[2] = (bf16)xr[it].z; o[3] = (bf16)xr[it].w;
            *(bf16x4*)(xs + row * 512 + ((c4 * 8) ^ ((row & 7) << 4))) = o;
        }
    }
    __syncthreads();

    bf16x4 qf[4][2];   // [qt(token)][ct(chan)] B-frag for scores
    bf16x4 kf[4][2];   // [kt(token)][ct(chan)] A-frag for scores
    bf16x4 pB[4][4];   // [qt][kt]  UNNORMALIZED e == PV B-frag (parks thru V)
    float  rsv[4];     // [qt] 1/sum, applied to oT after PV
    bf16x4 vf[2][4];   // [dt][kt]  A-frag for PV

    // ---- merged QK pass (SWAPPED, depth-2, ROLLED loop trip 7 + tail) ----
    //   C'[chan=4g+r (+16*mt)][token=c (+16*nt)] == scores frag layout.
    {
        f32x4 acc[4][4];   // [mt][nt]
        #pragma unroll
        for (int mt = 0; mt < 4; ++mt)
            #pragma unroll
            for (int nt = 0; nt < 4; ++nt)
                acc[mt][nt] = (f32x4){0.f, 0.f, 0.f, 0.f};

        bf16x8 xcur[4], xnxt[4];
        #pragma unroll
        for (int nt = 0; nt < 4; ++nt)
            xcur[nt] = ldsA(xs, nt * 16 + c, g * 16);

        #pragma unroll 1
        for (int kk = 0; kk < 7; ++kk) {
            #pragma unroll
            for (int mt = 0; mt < 4; ++mt)
                wnxt[mt] = *(const bf16x8*)(wt_qkv + cbase(mt) * 256 + (kk + 1) * 32 + g * 8);
            #pragma unroll
            for (int nt = 0; nt < 4; ++nt)
                xnxt[nt] = ldsA(xs, nt * 16 + c, (kk + 1) * 64 + g * 16);
            #pragma unroll
            for (int mt = 0; mt < 4; ++mt)
                #pragma unroll
                for (int nt = 0; nt < 4; ++nt)
                    acc[mt][nt] = __builtin_amdgcn_mfma_f32_16x16x32_bf16(wcur[mt], xcur[nt], acc[mt][nt], 0, 0, 0);
            #pragma unroll
            for (int mt = 0; mt < 4; ++mt) wcur[mt] = wnxt[mt];
            #pragma unroll
            for (int nt = 0; nt < 4; ++nt) xcur[nt] = xnxt[nt];
        }
        #pragma unroll
        for (int mt = 0; mt < 4; ++mt)
            #pragma unroll
            for (int nt = 0; nt < 4; ++nt)
                acc[mt][nt] = __builtin_amdgcn_mfma_f32_16x16x32_bf16(wcur[mt], xcur[nt], acc[mt][nt], 0, 0, 0);

        // epilogue: +bias (per-chan, one float4 per tile); NO transpose.
        #pragma unroll
        for (int mt = 0; mt < 2; ++mt) {
            f32x4 bq = *(const f32x4*)(qkv_b + h * 32 + mt * 16 + 4 * g);
            #pragma unroll
            for (int nt = 0; nt < 4; ++nt)
                #pragma unroll
                for (int r = 0; r < 4; ++r)
                    qf[nt][mt][r] = (bf16)(acc[mt][nt][r] + bq[r] * SCALE_Q);
        }
        #pragma unroll
        for (int mt = 0; mt < 2; ++mt) {
            f32x4 bk = *(const f32x4*)(qkv_b + 256 + h * 32 + mt * 16 + 4 * g);
            #pragma unroll
            for (int nt = 0; nt < 4; ++nt)
                #pragma unroll
                for (int r = 0; r < 4; ++r)
                    kf[nt][mt][r] = (bf16)(acc[mt + 2][nt][r] + bk[r]);
        }
    }

    const int colV = 512 + h * 32 + c;

    // pipeline registers for V / proj passes
    bf16x8 bcur[2][2], bnxt[2][2];        // [ni][hf]
    bf16x8 acur[2][4], anxt[2][4];        // [hf][mi]

    // ---- scores + softmax (per qt; last qt prefetches V(0)) ----
    {
        const float* sbh = sb + (size_t)h * 4096;
        const float* smw = sm + (size_t)(b & 63) * 4096;
        #pragma unroll
        for (int qt = 0; qt < 4; ++qt) {
            f32x4 sbv[4], smv[4];
            #pragma unroll
            for (int kt = 0; kt < 4; ++kt)
                sbv[kt] = *(const f32x4*)(sbh + (kt * 4 + qt) * 256 + lane * 4);
            #pragma unroll
            for (int kt = 0; kt < 4; ++kt)
                smv[kt] = *(const f32x4*)(smw + (kt * 4 + qt) * 256 + lane * 4);

            f32x4 sT[4];
            __builtin_amdgcn_s_setprio(1);
            #pragma unroll
            for (int kt = 0; kt < 4; ++kt) {
                sT[kt] = (f32x4){0.f, 0.f, 0.f, 0.f};
                sT[kt] = mfma16(kf[kt][0], qf[qt][0], sT[kt]);
                sT[kt] = mfma16(kf[kt][1], qf[qt][1], sT[kt]);
            }
            __builtin_amdgcn_s_setprio(0);
            if (qt == 3) {   // prefetch V's k2=0 under the softmax tail
                #pragma unroll
                for (int ni = 0; ni < 2; ++ni)
                    #pragma unroll
                    for (int hf = 0; hf < 2; ++hf)
                        bcur[ni][hf] = ldB(wt_qkv, colV + ni * 16, 0, hf, g);
                #pragma unroll
                for (int hf = 0; hf < 2; ++hf)
                    #pragma unroll
                    for (int mi = 0; mi < 4; ++mi)
                        acur[hf][mi] = ldsA(xs, mi * 16 + c, hf * 64 + g * 16);
            }
            #pragma unroll
            for (int kt = 0; kt < 4; ++kt)
                #pragma unroll
                for (int r = 0; r < 4; ++r)
                    sT[kt][r] += sbv[kt][r] + smv[kt][r];
            // tree max over the 16 in-lane values, then cross-lane
            f32x4 mx4;
            #pragma unroll
            for (int r = 0; r < 4; ++r)
                mx4[r] = fmaxf(fmaxf(sT[0][r], sT[1][r]), fmaxf(sT[2][r], sT[3][r]));
            float m = fmaxf(fmaxf(mx4[0], mx4[1]), fmaxf(mx4[2], mx4[3]));
            m = fmaxf(m, __shfl_xor(m, 16));
            m = fmaxf(m, __shfl_xor(m, 32));
            f32x4 sm4 = (f32x4){0.f, 0.f, 0.f, 0.f};
            #pragma unroll
            for (int kt = 0; kt < 4; ++kt)
                #pragma unroll
                for (int r = 0; r < 4; ++r) {
                    float e = __expf(sT[kt][r] - m);
                    sT[kt][r] = e;
                    sm4[r] += e;
                }
            float sum = (sm4[0] + sm4[1]) + (sm4[2] + sm4[3]);
            sum += __shfl_xor(sum, 16);
            sum += __shfl_xor(sum, 32);
            rsv[qt] = 1.f / sum;
            // store UNNORMALIZED e (<=1, bf16-safe); norm folded into oT
            #pragma unroll
            for (int kt = 0; kt < 4; ++kt)
                #pragma unroll
                for (int r = 0; r < 4; ++r) pB[qt][kt][r] = (bf16)sT[kt][r];
        }
    }

    // ---- pass V (pipelined, ROLLED trip 3 + tail; bcur/acur hold V(0)) ----
    {
        f32x4 acc[2][4];
        #pragma unroll
        for (int dt = 0; dt < 2; ++dt)
            #pragma unroll
            for (int mi = 0; mi < 4; ++mi)
                acc[dt][mi] = (f32x4){0.f, 0.f, 0.f, 0.f};
        #pragma unroll 1
        for (int k2 = 0; k2 < 3; ++k2) {
            #pragma unroll
            for (int dt = 0; dt < 2; ++dt)
                #pragma unroll
                for (int hf = 0; hf < 2; ++hf)
                    bnxt[dt][hf] = ldB(wt_qkv, colV + dt * 16, k2 + 1, hf, g);
            #pragma unroll
            for (int hf = 0; hf < 2; ++hf)
                #pragma unroll
                for (int mi = 0; mi < 4; ++mi)
                    anxt[hf][mi] = ldsA(xs, mi * 16 + c, (k2 + 1) * 128 + hf * 64 + g * 16);
            #pragma unroll
            for (int hf = 0; hf < 2; ++hf)
                #pragma unroll
                for (int dt = 0; dt < 2; ++dt)
                    #pragma unroll
                    for (int mi = 0; mi < 4; ++mi)
                        acc[dt][mi] = __builtin_amdgcn_mfma_f32_16x16x32_bf16(acur[hf][mi], bcur[dt][hf], acc[dt][mi], 0, 0, 0);
            #pragma unroll
            for (int dt = 0; dt < 2; ++dt)
                #pragma unroll
                for (int hf = 0; hf < 2; ++hf)
                    bcur[dt][hf] = bnxt[dt][hf];
            #pragma unroll
            for (int hf = 0; hf < 2; ++hf)
                #pragma unroll
                for (int mi = 0; mi < 4; ++mi)
                    acur[hf][mi] = anxt[hf][mi];
        }
        #pragma unroll
        for (int hf = 0; hf < 2; ++hf)
            #pragma unroll
            for (int dt = 0; dt < 2; ++dt)
                #pragma unroll
                for (int mi = 0; mi < 4; ++mi)
                    acc[dt][mi] = __builtin_amdgcn_mfma_f32_16x16x32_bf16(acur[hf][mi], bcur[dt][hf], acc[dt][mi], 0, 0, 0);
        #pragma unroll
        for (int dt = 0; dt < 2; ++dt) {
            float vb = qkv_b[512 + h * 32 + dt * 16 + c];
            #pragma unroll
            for (int kt = 0; kt < 4; ++kt)
                #pragma unroll
                for (int r = 0; r < 4; ++r) vf[dt][kt][r] = (bf16)(acc[dt][kt][r] + vb);
        }
    }

    // ---- PV: write straight to xs2; fold 1/sum here ----
    __builtin_amdgcn_s_setprio(1);
    #pragma unroll
    for (int qt = 0; qt < 4; ++qt) {
        int row = qt * 16 + c;
        #pragma unroll
        for (int dt = 0; dt < 2; ++dt) {
            f32x4 oT = (f32x4){0.f, 0.f, 0.f, 0.f};
            #pragma unroll
            for (int kt = 0; kt < 4; ++kt)
                oT = mfma16(vf[dt][kt], pB[qt][kt], oT);
            int cbyte = h * 64 + dt * 32 + g * 8;
            bf16x4 o;
            #pragma unroll
            for (int r = 0; r < 4; ++r) o[r] = (bf16)(oT[r] * rsv[qt]);
            *(bf16x4*)(xs2 + row * 512 + (cbyte ^ ((row & 7) << 4))) = o;
        }
    }
    __builtin_amdgcn_s_setprio(0);

    // prefetch proj's B(0) before the barrier (global load, no LDS dep)
    #pragma unroll
    for (int ni = 0; ni < 2; ++ni)
        #pragma unroll
        for (int hf = 0; hf < 2; ++hf)
            bcur[ni][hf] = ldB(wt_proj, h * 32 + ni * 16 + c, 0, hf, g);

    __syncthreads();   // single barrier: all PV writes to xs2 visible

    // ---- proj (pipelined, ROLLED trip 3 + tail; bcur holds proj(0)) ----
    {
        f32x4 po[2][4];
        #pragma unroll
        for (int ni = 0; ni < 2; ++ni)
            #pragma unroll
            for (int mi = 0; mi < 4; ++mi)
                po[ni][mi] = (f32x4){0.f, 0.f, 0.f, 0.f};

        #pragma unroll
        for (int hf = 0; hf < 2; ++hf)
            #pragma unroll
            for (int mi = 0; mi < 4; ++mi)
                acur[hf][mi] = ldsA(xs2, mi * 16 + c, hf * 64 + g * 16);

        #pragma unroll 1
        for (int k2 = 0; k2 < 3; ++k2) {
            #pragma unroll
            for (int ni = 0; ni < 2; ++ni)
                #pragma unroll
                for (int hf = 0; hf < 2; ++hf)
                    bnxt[ni][hf] = ldB(wt_proj, h * 32 + ni * 16 + c, k2 + 1, hf, g);
            #pragma unroll
            for (int hf = 0; hf < 2; ++hf)
                #pragma unroll
                for (int mi = 0; mi < 4; ++mi)
                    anxt[hf][mi] = ldsA(xs2, mi * 16 + c, (k2 + 1) * 128 + hf * 64 + g * 16);
            #pragma unroll
            for (int hf = 0; hf < 2; ++hf)
                #pragma unroll
                for (int ni = 0; ni < 2; ++ni)
                    #pragma unroll
                    for (int mi = 0; mi < 4; ++mi)
                        po[ni][mi] = __builtin_amdgcn_mfma_f32_16x16x32_bf16(acur[hf][mi], bcur[ni][hf], po[ni][mi], 0, 0, 0);
            #pragma unroll
            for (int ni = 0; ni < 2; ++ni)
                #pragma unroll
                for (int hf = 0; hf < 2; ++hf)
                    bcur[ni][hf] = bnxt[ni][hf];
            #pragma unroll
            for (int hf = 0; hf < 2; ++hf)
                #pragma unroll
                for (int mi = 0; mi < 4; ++mi)
                    acur[hf][mi] = anxt[hf][mi];
        }
        #pragma unroll
        for (int hf = 0; hf < 2; ++hf)
            #pragma unroll
            for (int ni = 0; ni < 2; ++ni)
                #pragma unroll
                for (int mi = 0; mi < 4; ++mi)
                    po[ni][mi] = __builtin_amdgcn_mfma_f32_16x16x32_bf16(acur[hf][mi], bcur[ni][hf], po[ni][mi], 0, 0, 0);

        float* outb = out + (size_t)b * (NTOK * 256);
        #pragma unroll
        for (int ni = 0; ni < 2; ++ni) {
            int col = h * 32 + ni * 16 + c;
            float pb = proj_b[col];
            #pragma unroll
            for (int mi = 0; mi < 4; ++mi) {
                #pragma unroll
                for (int r = 0; r < 4; ++r) {
                    int row = mi * 16 + g * 4 + r;
                    if (row < NTOK) outb[row * 256 + col] = po[ni][mi][r] + pb;
                }
            }
        }
    }
}

extern "C" void kernel_launch(void* const* d_in, const int* in_sizes, int n_in,
                              void* d_out, int out_size, void* d_ws, size_t ws_size,
                              hipStream_t stream) {
    const float* x          = (const float*)d_in[0];
    const float* mask       = (const float*)d_in[1];
    const float* qkv_w      = (const float*)d_in[2];
    const float* qkv_b      = (const float*)d_in[3];
    const float* proj_w     = (const float*)d_in[4];
    const float* proj_b     = (const float*)d_in[5];
    const float* bias_table = (const float*)d_in[6];
    const int*   rel_index  = (const int*)d_in[7];
    float* out = (float*)d_out;

    if (ws_size < WS_NEEDED) return;  // needs ~1.7 MB scratch

    char* ws = (char*)d_ws;
    bf16*  wt_qkv  = (bf16*)(ws + WT_QKV_OFF);
    bf16*  wt_proj = (bf16*)(ws + WT_PROJ_OFF);
    float* sbp     = (float*)(ws + SB_OFF);
    float* smp     = (float*)(ws + SM_OFF);

    prep_wqkv <<<768, 256, 0, stream>>>(qkv_w, wt_qkv);
    prep_wproj<<<256, 256, 0, stream>>>(proj_w, wt_proj);
    prep_sb   <<<128, 256, 0, stream>>>(bias_table, rel_index, sbp);
    prep_sm   <<<1024, 256, 0, stream>>>(mask, smp);

    fused_attn<<<4096, 512, 0, stream>>>(x, qkv_b, proj_b, wt_qkv, wt_proj, sbp, smp, out);
}